// Round 12
// baseline (174.836 us; speedup 1.0000x reference)
//
#include <hip/hip_runtime.h>

#define NN 100
#define CC 256
#define NKK 103
#define LDT 136    // depthT stride (bf16): 272 B rows; must be >= 128 (padded contraction range)
#define OTS 260    // out-transpose stride (f32): 1040 B rows; 1040 % 128 = 16 -> 2-way (free)
#define LQS 264    // gemm1 q-stage stride (bf16): 528 B rows; 528 % 128 = 16 -> 2-way (free)

typedef __bf16 bf16;
typedef __bf16 bf16x4 __attribute__((ext_vector_type(4)));
typedef __bf16 bf16x8 __attribute__((ext_vector_type(8)));
typedef float f32x4 __attribute__((ext_vector_type(4)));

// Per-batch scratch carved from the head of the out buffer (f32 units, 25600/batch):
//   [    0, 6400)  pw  bf16 [100][128]   (cols 100..127 junk -> masked in k2)
//   [ 6400, 6800)  dw  f32  [100][4]     (col 3 unused)
// kernel-2 block b reads ONLY batch b's scratch, all before overwriting out[b].

// kernel0: W (f32 [256][103]) -> Wt2 (bf16, FRAGMENT order) in workspace.
// Wt2[((J*8+f)*64 + lane)*8 + j] = W^T[J*16+ln16][f*32+g*8+j]  (lane=(g<<4)|ln16)
// -> gemm1's B-loads are lane-contiguous 1KB streams (4 txns/instr vs 64; r10 fix,
//    confirmed r11: gemm1 41 -> ~8 us).
__global__ void wl_frag(const float* __restrict__ W, bf16* __restrict__ Wt2)
{
    int idx = blockIdx.x * 256 + threadIdx.x;     // 7*8*64*8 = 28672
    if (idx < 7 * 8 * 64 * 8) {
        int j    = idx & 7;
        int lane = (idx >> 3) & 63;
        int f    = (idx >> 9) & 7;
        int J    = idx >> 12;
        int ka   = J * 16 + (lane & 15);
        if (ka > NKK - 1) ka = NKK - 1;           // clamped cols discarded in epilogue
        int k    = f * 32 + ((lane >> 4) << 3) + j;
        Wt2[idx] = (bf16)W[k * NKK + ka];
    }
}

// kernel1: dy = q@W + bias as a flat GEMM [51200][256] x [256][103].  (r11, unchanged)
__global__ __launch_bounds__(256, 4)
void gemm1(const float* __restrict__ query, const bf16* __restrict__ Wt2,
           const float* __restrict__ bwl, float* __restrict__ out)
{
    __shared__ __align__(16) bf16 ST[4][16][LQS];   // 33792 B; q-stage, then pw-stage
    const int t    = threadIdx.x;
    const int w    = t >> 6;
    const int lane = t & 63;
    const int ln16 = lane & 15;
    const int g    = lane >> 4;
    const int hi8  = g * 8;
    const int R0   = blockIdx.x * 64 + w * 16;     // wave's flat row tile (< 51200)

    // stage q rows R0..R0+15 (wave-local): 16 coalesced 1KB row reads
    const float* qb = query + (size_t)R0 * CC;
    #pragma unroll
    for (int p = 0; p < 16; ++p) {
        f32x4 v = *(const f32x4*)(qb + p * CC + lane * 4);
        bf16x4 s;
        #pragma unroll
        for (int i = 0; i < 4; ++i) s[i] = (bf16)v[i];
        *(bf16x4*)&ST[w][p][lane * 4] = s;
    }
    __syncthreads();

    // A fragments from LDS: row ln16, 8 col-frags (2-way banks, free)
    bf16x8 qfr[8];
    #pragma unroll
    for (int f = 0; f < 8; ++f)
        qfr[f] = *(const bf16x8*)&ST[w][ln16][f * 32 + hi8];

    f32x4 acc[7];
    #pragma unroll
    for (int J = 0; J < 7; ++J) acc[J] = (f32x4){0.f, 0.f, 0.f, 0.f};

    #pragma unroll
    for (int J = 0; J < 7; ++J) {
        const bf16* wb = Wt2 + (size_t)(J * 8) * 512 + lane * 8;   // lane-contiguous
        #pragma unroll
        for (int f = 0; f < 8; ++f) {
            bf16x8 bv = *(const bf16x8*)(wb + f * 512);
            acc[J] = __builtin_amdgcn_mfma_f32_16x16x32_bf16(qfr[f], bv, acc[J], 0, 0, 0);
        }
    }
    __syncthreads();   // q-stage reads done -> ST reuse for pw staging

    // epilogue: stage pw cols (kap in [3,103) -> LDS col kap-3); dw (kap<3) direct
    #pragma unroll
    for (int J = 0; J < 7; ++J) {
        int kap = J * 16 + ln16;
        float bw = (kap < NKK) ? bwl[kap] : 0.f;
        #pragma unroll
        for (int r = 0; r < 4; ++r) {
            float v = acc[J][r] + bw;
            int row = g * 4 + r;
            if (kap >= 3 && kap < NKK) {
                ST[w][row][kap - 3] = (bf16)v;
            } else if (J == 0 && kap < 3) {
                int nf  = R0 + row;
                int bbb = nf / 100, nnr = nf - bbb * 100;
                out[(size_t)bbb * 25600 + 6400 + nnr * 4 + kap] = v;   // dw f32
            }
        }
    }
    // wave-local read-back -> coalesced 256B pw row stores (pad cols masked in k2)
    #pragma unroll
    for (int p = 0; p < 4; ++p) {
        int row = p * 4 + g;                // 0..15
        int nf  = R0 + row;
        int bbb = nf / 100, nnr = nf - bbb * 100;
        bf16x8 vrow = *(const bf16x8*)&ST[w][row][ln16 * 8];
        *(bf16x8*)((bf16*)(out + (size_t)bbb * 25600) + nnr * 128 + ln16 * 8) = vrow;
    }
}

// kernel2: conv -> depthT(LDS) -> GEMM2 -> in-wave LN -> coalesced store.
// r12 changes vs r11:
//  * DWs reverted to stride 4 (exact r10 config -- A/B on the unexplained
//    41->63 us regression; stride-5 misalignment is suspect (a), session clock
//    variance is suspect (b))
//  * conv ks-loop s-split with ping-pong prefetch: load (s,ks+1) before
//    consuming (s,ks). Kills the per-ks exposed HBM latency (single-buffer WAR).
//    Register-neutral: xv[8]+xn[8] = 16 regs, same as old xv[2][8].
// SMEM: [0,69632) depthT bf16 [256][136] ; [69632,71232) dw f32 [100][4]
//       store phase: OT f32 [64][260] (66560 B) aliases depthT
__global__ __launch_bounds__(512, 4)
void conv_gemm2_ln(const float* __restrict__ value,
                   const float* __restrict__ gamma,
                   const float* __restrict__ beta,
                   float* __restrict__ out)
{
    __shared__ __align__(16) char SMEM[71232];
    bf16* depthT = (bf16*)SMEM;                       // [256][LDT]
    float (*DWs)[4] = (float(*)[4])(SMEM + 69632);    // [100][4]
    float* OT = (float*)SMEM;                         // [64][OTS]

    const int t    = threadIdx.x;
    const int w    = t >> 6;          // wave 0..7
    const int lane = t & 63;
    const int ln16 = lane & 15;
    const int g    = lane >> 4;
    const int hi8  = g * 8;
    const int b    = blockIdx.x;
    const int cb   = w * 16 + ln16;   // channel base 0..127; lane owns cb + 128*s

    float* ob = out + (size_t)b * 25600;
    const bf16*  pwb = (const bf16*)ob;               // [100][128]
    const float* vb  = value + (size_t)b * NN * CC;

    // stage dw -> LDS; prefetch (s=0, ks=0) value rows (m<32 always valid)
    if (t < 400) ((float*)DWs)[t] = ob[6400 + t];
    float xv[8];
    #pragma unroll
    for (int j = 0; j < 8; ++j)
        xv[j] = vb[(hi8 + j) * CC + cb];
    __syncthreads();   // DWs visible

    // ---- conv: depth[m][c] = relu(dw0*v[m][c-1]+dw1*v[m][c]+dw2*v[m][c+1]) ----
    // stored transposed: depthT[c][m], zero for m in [100,128); [128,136) pad never read
    #pragma unroll
    for (int s = 0; s < 2; ++s) {
        #pragma unroll
        for (int ks = 0; ks < 4; ++ks) {
            float xn[8];
            const bool more = (ks < 3) || (s == 0);
            const int  sn   = (ks < 3) ? s : 1;
            const int  kn   = (ks < 3) ? (ks + 1) : 0;
            if (more) {   // issue next-(s,ks) loads BEFORE the conv chain
                #pragma unroll
                for (int j = 0; j < 8; ++j) {
                    int m = kn * 32 + hi8 + j;
                    xn[j] = (m < NN) ? vb[m * CC + cb + 128 * sn] : 0.f;
                }
            }
            const int c = cb + 128 * s;
            bf16x8 dv;
            #pragma unroll
            for (int j = 0; j < 8; ++j) {
                int  m  = ks * 32 + hi8 + j;
                bool mv = (m < NN);
                int  mc = mv ? m : (NN - 1);
                float w0 = DWs[mc][0], w1 = DWs[mc][1], w2 = DWs[mc][2];
                float x0 = xv[j];
                float xm = __shfl(x0, (lane - 1) & 63);
                float xp = __shfl(x0, (lane + 1) & 63);
                if (ln16 == 0)  xm = (mv && c > 0)      ? vb[m * CC + c - 1] : 0.f;
                if (ln16 == 15) xp = (mv && c + 1 < CC) ? vb[m * CC + c + 1] : 0.f;
                float d = w0 * xm + w1 * x0 + w2 * xp;
                dv[j] = (bf16)(mv ? fmaxf(d, 0.f) : 0.f);
            }
            *(bf16x8*)&depthT[(cb + 128 * s) * LDT + ks * 32 + hi8] = dv;
            if (more) {
                #pragma unroll
                for (int j = 0; j < 8; ++j) xv[j] = xn[j];
            }
        }
    }

    // issue pw A-fragment loads BEFORE the barrier: latency drains under it
    bf16x8 av[4];
    if (w < 7) {
        const int arow = (w * 16 + ln16 < NN) ? (w * 16 + ln16) : (NN - 1); // rows>=100 discarded
        #pragma unroll
        for (int ks = 0; ks < 4; ++ks)
            av[ks] = *(const bf16x8*)(pwb + arow * 128 + ks * 32 + hi8);
    }
    __syncthreads();   // depthT ready

    // ---- GEMM2 + in-wave LN: wave w<7 owns out rows 16w..16w+15, all 256 cols ----
    f32x4 acc[16];
    #pragma unroll
    for (int ct = 0; ct < 16; ++ct) acc[ct] = (f32x4){0.f, 0.f, 0.f, 0.f};
    float mu[4], rs[4];

    if (w < 7) {
        // pw cols >=100 are junk (NaN*0=NaN) -> zero them; depthT rows >=100 are 0.
        #pragma unroll
        for (int j = 0; j < 8; ++j)
            av[3][j] = (96 + hi8 + j < NN) ? av[3][j] : (bf16)0.f;

        #pragma unroll
        for (int ct = 0; ct < 16; ++ct) {
            #pragma unroll
            for (int ks = 0; ks < 4; ++ks) {
                bf16x8 bv = *(const bf16x8*)&depthT[(ct * 16 + ln16) * LDT + ks * 32 + hi8];
                acc[ct] = __builtin_amdgcn_mfma_f32_16x16x32_bf16(av[ks], bv, acc[ct], 0, 0, 0);
            }
        }
        // LN fully in-wave: row n = 16w+g*4+r; (ct, ln16) spans all 256 cols
        #pragma unroll
        for (int r = 0; r < 4; ++r) {
            float s1 = 0.f, s2 = 0.f;
            #pragma unroll
            for (int ct = 0; ct < 16; ++ct) { float a = acc[ct][r]; s1 += a; s2 += a * a; }
            #pragma unroll
            for (int mk = 1; mk < 16; mk <<= 1) {
                s1 += __shfl_xor(s1, mk);
                s2 += __shfl_xor(s2, mk);
            }
            float m_ = s1 * (1.f / 256.f);
            float v_ = s2 * (1.f / 256.f) - m_ * m_;
            mu[r] = m_;
            rs[r] = rsqrtf(fmaxf(v_, 0.f) + 1e-5f);
        }
    }
    __syncthreads();   // all depthT/pw reads done -> OT alias + out overwrite safe

    // ---- normalize + transpose through LDS, two half-passes of 64 rows ----
    #pragma unroll
    for (int h = 0; h < 2; ++h) {
        if (w >= 4 * h && w < 4 * h + 4 && w < 7) {
            const int slot = w - 4 * h;
            #pragma unroll
            for (int ct = 0; ct < 16; ++ct) {
                const float gmv = gamma[ct * 16 + ln16], btv = beta[ct * 16 + ln16];
                #pragma unroll
                for (int r = 0; r < 4; ++r)
                    OT[(slot * 16 + g * 4 + r) * OTS + ct * 16 + ln16] =
                        (acc[ct][r] - mu[r]) * rs[r] * gmv + btv;
            }
        }
        __syncthreads();
        const int rows = h ? 36 : 64;        // h=1: rows 64..99 only
        #pragma unroll
        for (int p = 0; p < 8; ++p) {
            int idx = p * 512 + t;
            if (idx < rows * 64) {
                int row = idx >> 6, c4 = (idx & 63) << 2;
                *(f32x4*)(ob + (size_t)(64 * h + row) * CC + c4) = *(const f32x4*)&OT[row * OTS + c4];
            }
        }
        if (h == 0) __syncthreads();
    }
}

extern "C" void kernel_launch(void* const* d_in, const int* in_sizes, int n_in,
                              void* d_out, int out_size, void* d_ws, size_t ws_size,
                              hipStream_t stream) {
    const float* query = (const float*)d_in[0];
    const float* value = (const float*)d_in[1];
    const float* W     = (const float*)d_in[2];
    const float* bwl   = (const float*)d_in[3];
    const float* gamma = (const float*)d_in[4];
    const float* beta  = (const float*)d_in[5];
    float* out = (float*)d_out;
    bf16* Wt2 = (bf16*)d_ws;   // 7*8*64*8*2 = 57344 B fragment-ordered W

    wl_frag<<<dim3(112), dim3(256), 0, stream>>>(W, Wt2);
    gemm1<<<dim3(800), dim3(256), 0, stream>>>(query, Wt2, bwl, out);
    conv_gemm2_ln<<<dim3(512), dim3(512), 0, stream>>>(value, gamma, beta, out);
}

// Round 13
// 174.208 us; speedup vs baseline: 1.0036x; 1.0036x over previous
//
#include <hip/hip_runtime.h>

#define NN 100
#define CC 256
#define NKK 103
#define LDT 136    // depthT stride (bf16): 272 B rows; must be >= 128 (padded contraction range)
#define OTS 260    // out-transpose stride (f32): 1040 B rows; 1040 % 128 = 16 -> 2-way (free)
#define LQS 264    // gemm1 q-stage stride (bf16): 528 B rows; 528 % 128 = 16 -> 2-way (free)

typedef __bf16 bf16;
typedef __bf16 bf16x4 __attribute__((ext_vector_type(4)));
typedef __bf16 bf16x8 __attribute__((ext_vector_type(8)));
typedef float f32x4 __attribute__((ext_vector_type(4)));

// Per-batch scratch carved from the head of the out buffer (f32 units, 25600/batch):
//   [    0, 6400)  pw  bf16 [100][128]   (cols 100..127 junk -> masked in k2)
//   [ 6400, 6800)  dw  f32  [100][4]     (col 3 unused)
// kernel-2 block b reads ONLY batch b's scratch, all before overwriting out[b].

// kernel0: W (f32 [256][103]) -> Wt2 (bf16, FRAGMENT order) in workspace.
// Wt2[((J*8+f)*64 + lane)*8 + j] = W^T[J*16+ln16][f*32+g*8+j]  (lane=(g<<4)|ln16)
// -> gemm1's B-loads are lane-contiguous 1KB streams (4 txns/instr vs 64; r10 fix,
//    confirmed r11: gemm1 41 -> sub-15 us).
__global__ void wl_frag(const float* __restrict__ W, bf16* __restrict__ Wt2)
{
    int idx = blockIdx.x * 256 + threadIdx.x;     // 7*8*64*8 = 28672
    if (idx < 7 * 8 * 64 * 8) {
        int j    = idx & 7;
        int lane = (idx >> 3) & 63;
        int f    = (idx >> 9) & 7;
        int J    = idx >> 12;
        int ka   = J * 16 + (lane & 15);
        if (ka > NKK - 1) ka = NKK - 1;           // clamped cols discarded in epilogue
        int k    = f * 32 + ((lane >> 4) << 3) + j;
        Wt2[idx] = (bf16)W[k * NKK + ka];
    }
}

// kernel1: dy = q@W + bias as a flat GEMM [51200][256] x [256][103].  (r11, unchanged)
__global__ __launch_bounds__(256, 4)
void gemm1(const float* __restrict__ query, const bf16* __restrict__ Wt2,
           const float* __restrict__ bwl, float* __restrict__ out)
{
    __shared__ __align__(16) bf16 ST[4][16][LQS];   // 33792 B; q-stage, then pw-stage
    const int t    = threadIdx.x;
    const int w    = t >> 6;
    const int lane = t & 63;
    const int ln16 = lane & 15;
    const int g    = lane >> 4;
    const int hi8  = g * 8;
    const int R0   = blockIdx.x * 64 + w * 16;     // wave's flat row tile (< 51200)

    // stage q rows R0..R0+15 (wave-local): 16 coalesced 1KB row reads
    const float* qb = query + (size_t)R0 * CC;
    #pragma unroll
    for (int p = 0; p < 16; ++p) {
        f32x4 v = *(const f32x4*)(qb + p * CC + lane * 4);
        bf16x4 s;
        #pragma unroll
        for (int i = 0; i < 4; ++i) s[i] = (bf16)v[i];
        *(bf16x4*)&ST[w][p][lane * 4] = s;
    }
    __syncthreads();

    // A fragments from LDS: row ln16, 8 col-frags (2-way banks, free)
    bf16x8 qfr[8];
    #pragma unroll
    for (int f = 0; f < 8; ++f)
        qfr[f] = *(const bf16x8*)&ST[w][ln16][f * 32 + hi8];

    f32x4 acc[7];
    #pragma unroll
    for (int J = 0; J < 7; ++J) acc[J] = (f32x4){0.f, 0.f, 0.f, 0.f};

    #pragma unroll
    for (int J = 0; J < 7; ++J) {
        const bf16* wb = Wt2 + (size_t)(J * 8) * 512 + lane * 8;   // lane-contiguous
        #pragma unroll
        for (int f = 0; f < 8; ++f) {
            bf16x8 bv = *(const bf16x8*)(wb + f * 512);
            acc[J] = __builtin_amdgcn_mfma_f32_16x16x32_bf16(qfr[f], bv, acc[J], 0, 0, 0);
        }
    }
    __syncthreads();   // q-stage reads done -> ST reuse for pw staging

    // epilogue: stage pw cols (kap in [3,103) -> LDS col kap-3); dw (kap<3) direct
    #pragma unroll
    for (int J = 0; J < 7; ++J) {
        int kap = J * 16 + ln16;
        float bw = (kap < NKK) ? bwl[kap] : 0.f;
        #pragma unroll
        for (int r = 0; r < 4; ++r) {
            float v = acc[J][r] + bw;
            int row = g * 4 + r;
            if (kap >= 3 && kap < NKK) {
                ST[w][row][kap - 3] = (bf16)v;
            } else if (J == 0 && kap < 3) {
                int nf  = R0 + row;
                int bbb = nf / 100, nnr = nf - bbb * 100;
                out[(size_t)bbb * 25600 + 6400 + nnr * 4 + kap] = v;   // dw f32
            }
        }
    }
    // wave-local read-back -> coalesced 256B pw row stores (pad cols masked in k2)
    #pragma unroll
    for (int p = 0; p < 4; ++p) {
        int row = p * 4 + g;                // 0..15
        int nf  = R0 + row;
        int bbb = nf / 100, nnr = nf - bbb * 100;
        bf16x8 vrow = *(const bf16x8*)&ST[w][row][ln16 * 8];
        *(bf16x8*)((bf16*)(out + (size_t)bbb * 25600) + nnr * 128 + ln16 * 8) = vrow;
    }
}

// kernel2: conv -> depthT(LDS) -> GEMM2 -> in-wave LN -> coalesced store.
// EXACT r10 body (best measured: 41.0 us, WRITE = ideal 51200 KB, VGPR 60, no spill).
// r12's s-split ping-pong reverted: it cost +4 VGPR, +3MB spill-writes, +0.5M
// conflicts for zero time gain. Consolidation round.
// SMEM: [0,69632) depthT bf16 [256][136] ; [69632,71232) dw f32 [100][4]
//       store phase: OT f32 [64][260] (66560 B) aliases depthT
__global__ __launch_bounds__(512, 4)
void conv_gemm2_ln(const float* __restrict__ value,
                   const float* __restrict__ gamma,
                   const float* __restrict__ beta,
                   float* __restrict__ out)
{
    __shared__ __align__(16) char SMEM[71232];
    bf16* depthT = (bf16*)SMEM;                       // [256][LDT]
    float (*DWs)[4] = (float(*)[4])(SMEM + 69632);    // [100][4]
    float* OT = (float*)SMEM;                         // [64][OTS]

    const int t    = threadIdx.x;
    const int w    = t >> 6;          // wave 0..7
    const int lane = t & 63;
    const int ln16 = lane & 15;
    const int g    = lane >> 4;
    const int hi8  = g * 8;
    const int b    = blockIdx.x;
    const int cb   = w * 16 + ln16;   // channel base 0..127; lane owns cb + 128*s

    float* ob = out + (size_t)b * 25600;
    const bf16*  pwb = (const bf16*)ob;               // [100][128]
    const float* vb  = value + (size_t)b * NN * CC;

    // stage dw -> LDS; prefetch ks=0 value (m<32 always valid)
    if (t < 400) ((float*)DWs)[t] = ob[6400 + t];
    float xv[2][8];
    #pragma unroll
    for (int s = 0; s < 2; ++s)
        #pragma unroll
        for (int j = 0; j < 8; ++j)
            xv[s][j] = vb[(hi8 + j) * CC + cb + 128 * s];
    __syncthreads();   // DWs visible

    // ---- conv: depth[m][c] = relu(dw0*v[m][c-1]+dw1*v[m][c]+dw2*v[m][c+1]) ----
    // stored transposed: depthT[c][m], zero for m in [100,128); [128,136) pad never read
    #pragma unroll
    for (int ks = 0; ks < 4; ++ks) {
        if (ks) {
            #pragma unroll
            for (int s = 0; s < 2; ++s)
                #pragma unroll
                for (int j = 0; j < 8; ++j) {
                    int m = ks * 32 + hi8 + j;
                    xv[s][j] = (m < NN) ? vb[m * CC + cb + 128 * s] : 0.f;
                }
        }
        bf16x8 dv[2];
        #pragma unroll
        for (int j = 0; j < 8; ++j) {
            int  m  = ks * 32 + hi8 + j;
            bool mv = (m < NN);
            int  mc = mv ? m : (NN - 1);
            float w0 = DWs[mc][0], w1 = DWs[mc][1], w2 = DWs[mc][2];
            #pragma unroll
            for (int s = 0; s < 2; ++s) {
                int c = cb + 128 * s;
                float x0 = xv[s][j];
                float xm = __shfl(x0, (lane - 1) & 63);
                float xp = __shfl(x0, (lane + 1) & 63);
                if (ln16 == 0)  xm = (mv && c > 0)      ? vb[m * CC + c - 1] : 0.f;
                if (ln16 == 15) xp = (mv && c + 1 < CC) ? vb[m * CC + c + 1] : 0.f;
                float d = w0 * xm + w1 * x0 + w2 * xp;
                dv[s][j] = (bf16)(mv ? fmaxf(d, 0.f) : 0.f);
            }
        }
        #pragma unroll
        for (int s = 0; s < 2; ++s)
            *(bf16x8*)&depthT[(cb + 128 * s) * LDT + ks * 32 + hi8] = dv[s];
    }

    // issue pw A-fragment loads BEFORE the barrier: latency drains under it
    bf16x8 av[4];
    if (w < 7) {
        const int arow = (w * 16 + ln16 < NN) ? (w * 16 + ln16) : (NN - 1); // rows>=100 discarded
        #pragma unroll
        for (int ks = 0; ks < 4; ++ks)
            av[ks] = *(const bf16x8*)(pwb + arow * 128 + ks * 32 + hi8);
    }
    __syncthreads();   // depthT ready

    // ---- GEMM2 + in-wave LN: wave w<7 owns out rows 16w..16w+15, all 256 cols ----
    f32x4 acc[16];
    #pragma unroll
    for (int ct = 0; ct < 16; ++ct) acc[ct] = (f32x4){0.f, 0.f, 0.f, 0.f};
    float mu[4], rs[4];

    if (w < 7) {
        // pw cols >=100 are junk (NaN*0=NaN) -> zero them; depthT rows >=100 are 0.
        #pragma unroll
        for (int j = 0; j < 8; ++j)
            av[3][j] = (96 + hi8 + j < NN) ? av[3][j] : (bf16)0.f;

        #pragma unroll
        for (int ct = 0; ct < 16; ++ct) {
            #pragma unroll
            for (int ks = 0; ks < 4; ++ks) {
                bf16x8 bv = *(const bf16x8*)&depthT[(ct * 16 + ln16) * LDT + ks * 32 + hi8];
                acc[ct] = __builtin_amdgcn_mfma_f32_16x16x32_bf16(av[ks], bv, acc[ct], 0, 0, 0);
            }
        }
        // LN fully in-wave: row n = 16w+g*4+r; (ct, ln16) spans all 256 cols
        #pragma unroll
        for (int r = 0; r < 4; ++r) {
            float s1 = 0.f, s2 = 0.f;
            #pragma unroll
            for (int ct = 0; ct < 16; ++ct) { float a = acc[ct][r]; s1 += a; s2 += a * a; }
            #pragma unroll
            for (int mk = 1; mk < 16; mk <<= 1) {
                s1 += __shfl_xor(s1, mk);
                s2 += __shfl_xor(s2, mk);
            }
            float m_ = s1 * (1.f / 256.f);
            float v_ = s2 * (1.f / 256.f) - m_ * m_;
            mu[r] = m_;
            rs[r] = rsqrtf(fmaxf(v_, 0.f) + 1e-5f);
        }
    }
    __syncthreads();   // all depthT/pw reads done -> OT alias + out overwrite safe

    // ---- normalize + transpose through LDS, two half-passes of 64 rows ----
    #pragma unroll
    for (int h = 0; h < 2; ++h) {
        if (w >= 4 * h && w < 4 * h + 4 && w < 7) {
            const int slot = w - 4 * h;
            #pragma unroll
            for (int ct = 0; ct < 16; ++ct) {
                const float gmv = gamma[ct * 16 + ln16], btv = beta[ct * 16 + ln16];
                #pragma unroll
                for (int r = 0; r < 4; ++r)
                    OT[(slot * 16 + g * 4 + r) * OTS + ct * 16 + ln16] =
                        (acc[ct][r] - mu[r]) * rs[r] * gmv + btv;
            }
        }
        __syncthreads();
        const int rows = h ? 36 : 64;        // h=1: rows 64..99 only
        #pragma unroll
        for (int p = 0; p < 8; ++p) {
            int idx = p * 512 + t;
            if (idx < rows * 64) {
                int row = idx >> 6, c4 = (idx & 63) << 2;
                *(f32x4*)(ob + (size_t)(64 * h + row) * CC + c4) = *(const f32x4*)&OT[row * OTS + c4];
            }
        }
        if (h == 0) __syncthreads();
    }
}

extern "C" void kernel_launch(void* const* d_in, const int* in_sizes, int n_in,
                              void* d_out, int out_size, void* d_ws, size_t ws_size,
                              hipStream_t stream) {
    const float* query = (const float*)d_in[0];
    const float* value = (const float*)d_in[1];
    const float* W     = (const float*)d_in[2];
    const float* bwl   = (const float*)d_in[3];
    const float* gamma = (const float*)d_in[4];
    const float* beta  = (const float*)d_in[5];
    float* out = (float*)d_out;
    bf16* Wt2 = (bf16*)d_ws;   // 7*8*64*8*2 = 57344 B fragment-ordered W

    wl_frag<<<dim3(112), dim3(256), 0, stream>>>(W, Wt2);
    gemm1<<<dim3(800), dim3(256), 0, stream>>>(query, Wt2, bwl, out);
    conv_gemm2_ln<<<dim3(512), dim3(512), 0, stream>>>(value, gamma, beta, out);
}